// Round 1
// 754.898 us; speedup vs baseline: 1.1793x; 1.1793x over previous
//
#include <hip/hip_runtime.h>
#include <cstdint>
#include <cstddef>

// Self-attention, DIM=4096, fp32 in/out — zero-workspace, round 5.
//
// Round-5 change vs round 4 (890 us): both GEMMs ported from the 128²-tile
// 2-barrier structure (805 TF, MfmaUtil 37% — the documented ~900 TF ceiling
// of that schedule) to a 256²-tile, BK=64, 8-wave, 4-phase-per-K-tile
// schedule with:
//   T2: st_16x32 LDS XOR-swizzle (byte ^= ((byte>>9)&1)<<5) — staging side
//       pre-swizzles the GLOBAL source (linear global_load_lds dest),
//       ds_read applies the same involution (folds to lane-const XOR).
//   T3: 4 phases/K-tile, 16 MFMA each, reads {12,4,8,0} per phase,
//       raw s_barrier (NOT __syncthreads — that drains vmcnt(0)).
//   T4: counted vmcnt(4), once per K-tile, never 0 in the main loop.
//       While computing K-tile t (buf t&1) we stage K-tile t+1 into the
//       other buffer: 4 chunks BEFORE the vmcnt (they are the allowed
//       outstanding), 4 chunks in mid-phase-0. Tile t's own 8 loads were
//       issued one full K-tile (~4 phases) earlier -> wait is ~free.
//   T5: s_setprio(1) around each 16-MFMA cluster.
// LDS 128 KiB/block (2 x (A 32K + B 32K)), 512 threads, 1 block/CU.
//
// Buffer plan (harness restores d_in before every launch):
//   cvt#1: x -> d_out lo (xb), Wq -> d_out hi (wqb)
//   cvt#2: Wk -> Wq-buf lo (wkb), Wv -> Wq-buf hi (wvb)   [Wq consumed]
//   qkv  : q -> Wk-buf lo (bf16), k -> Wk-buf hi (bf16), v -> Wv-buf (fp32)
//   S    : q@k.T/64 -> d_out (fp32), then softmax*v in place.
//
// Fragment layouts per learn_hip m89/m91:
//   A frag:  A[m = lane&15][k = (lane>>4)*8 + j]   (per 32-wide k-slice)
//   B frag (B^T): B[n = lane&15][k = (lane>>4)*8 + j]
//   C/D: col = lane&15, row = (lane>>4)*4 + reg

#define NDIM 4096

typedef __bf16 bf16x8 __attribute__((ext_vector_type(8)));
typedef float f32x4 __attribute__((ext_vector_type(4)));
typedef unsigned short us8 __attribute__((ext_vector_type(8)));

__device__ __forceinline__ unsigned short f2bf(float f) {
  unsigned int u = __float_as_uint(f);
  return (unsigned short)((u + 0x7fffu + ((u >> 16) & 1u)) >> 16);  // RNE
}

__device__ __forceinline__ void async_copy16(void* lds, const void* g) {
  __builtin_amdgcn_global_load_lds(
      (__attribute__((address_space(1))) void*)(uintptr_t)g,
      (__attribute__((address_space(3))) void*)lds,
      16, 0, 0);
}

// two fp32->bf16 converts in one dispatch (blockIdx.y picks the pair)
__global__ __launch_bounds__(256) void cvt2_f32_to_bf16(
    const float* __restrict__ s0, unsigned short* __restrict__ d0,
    const float* __restrict__ s1, unsigned short* __restrict__ d1) {
  const float* src = blockIdx.y ? s1 : s0;
  unsigned short* dst = blockIdx.y ? d1 : d0;
  const int i = blockIdx.x * 256 + threadIdx.x;  // 8 floats per thread
  const float4* s = (const float4*)src;
  float4 a = s[2 * i];
  float4 b = s[2 * i + 1];
  us8 o;
  o[0] = f2bf(a.x); o[1] = f2bf(a.y); o[2] = f2bf(a.z); o[3] = f2bf(a.w);
  o[4] = f2bf(b.x); o[5] = f2bf(b.y); o[6] = f2bf(b.z); o[7] = f2bf(b.w);
  ((us8*)dst)[i] = o;
}

// ---- 256² / BK=64 / 8-wave / 4-phase counted-vmcnt GEMM core --------------
// LDS layout (ushort units): A0[16384] B0[16384] A1[16384] B1[16384]
// Within each 32 KiB tile: logical [256 rows][64 k] row-major, physical
// address = logical ^ ((logical>>9)&1)<<5  (st_16x32 swizzle, involution).

// stage chunks A0,A2,B0,B1 of the NEXT K-tile into the other buffer
#define STG4A(Ao, Bo, kn)                                        \
  async_copy16((Ao) + t * 8,          Asrc + (kn));              \
  async_copy16((Ao) + 8192 + t * 8,   Asrc + (kn) + 524288);     \
  async_copy16((Bo) + t * 8,          Bsrc + (kn));              \
  async_copy16((Bo) + 4096 + t * 8,   Bsrc + (kn) + 262144);

// stage chunks A1,A3,B2,B3
#define STG4B(Ao, Bo, kn)                                        \
  async_copy16((Ao) + 4096 + t * 8,   Asrc + (kn) + 262144);     \
  async_copy16((Ao) + 12288 + t * 8,  Asrc + (kn) + 786432);     \
  async_copy16((Bo) + 8192 + t * 8,   Bsrc + (kn) + 524288);     \
  async_copy16((Bo) + 12288 + t * 8,  Bsrc + (kn) + 786432);

#define RDA(Ac, ROFF)                                                          \
  _Pragma("unroll") for (int i = 0; i < 4; ++i) {                              \
    a[i][0] = *(const bf16x8*)((const char*)(Ac) + aob + ((ROFF) + i) * 2048); \
    a[i][1] = *(const bf16x8*)((const char*)(Ac) + aob + ((ROFF) + i) * 2048 + 64); \
  }

#define RDB(Bc, J0)                                                            \
  _Pragma("unroll") for (int jj = 0; jj < 2; ++jj) {                           \
    b[(J0) + jj][0] = *(const bf16x8*)((const char*)(Bc) + bob + ((J0) + jj) * 2048); \
    b[(J0) + jj][1] = *(const bf16x8*)((const char*)(Bc) + bob + ((J0) + jj) * 2048 + 64); \
  }

#define MFMA16(IO, J0)                                                         \
  _Pragma("unroll") for (int i = 0; i < 4; ++i)                                \
  _Pragma("unroll") for (int jj = 0; jj < 2; ++jj)                             \
  _Pragma("unroll") for (int ks = 0; ks < 2; ++ks)                             \
    acc[(IO) + i][(J0) + jj] = __builtin_amdgcn_mfma_f32_16x16x32_bf16(        \
        a[i][ks], b[(J0) + jj][ks], acc[(IO) + i][(J0) + jj], 0, 0, 0);

// One K-tile: compute (Ac,Bc); optionally stage next K-tile into (Ao,Bo).
// VM is a literal token (4 steady-state, 0 for the tail).
#define KTILE(Ac, Bc, Ao, Bo, kn, VM, DOSTAGE)                                 \
  {                                                                            \
    if (DOSTAGE) { STG4A(Ao, Bo, kn) }                                         \
    asm volatile("s_waitcnt vmcnt(" #VM ")" ::: "memory");                     \
    __builtin_amdgcn_s_barrier();                                              \
    __builtin_amdgcn_sched_barrier(0);                                         \
    RDA(Ac, 0)                                                                 \
    RDB(Bc, 0)                                                                 \
    if (DOSTAGE) { STG4B(Ao, Bo, kn) }                                         \
    __builtin_amdgcn_s_barrier();                                              \
    __builtin_amdgcn_sched_barrier(0);                                         \
    __builtin_amdgcn_s_setprio(1);                                             \
    MFMA16(0, 0)                                                               \
    __builtin_amdgcn_s_setprio(0);                                             \
    __builtin_amdgcn_s_barrier();                                              \
    __builtin_amdgcn_sched_barrier(0);                                         \
    RDB(Bc, 2)                                                                 \
    __builtin_amdgcn_s_barrier();                                              \
    __builtin_amdgcn_sched_barrier(0);                                         \
    __builtin_amdgcn_s_setprio(1);                                             \
    MFMA16(0, 2)                                                               \
    __builtin_amdgcn_s_setprio(0);                                             \
    __builtin_amdgcn_s_barrier();                                              \
    __builtin_amdgcn_sched_barrier(0);                                         \
    RDA(Ac, 4)                                                                 \
    __builtin_amdgcn_s_barrier();                                              \
    __builtin_amdgcn_sched_barrier(0);                                         \
    __builtin_amdgcn_s_setprio(1);                                             \
    MFMA16(4, 2)                                                               \
    __builtin_amdgcn_s_setprio(0);                                             \
    __builtin_amdgcn_s_barrier();                                              \
    __builtin_amdgcn_sched_barrier(0);                                         \
    __builtin_amdgcn_s_setprio(1);                                             \
    MFMA16(4, 0)                                                               \
    __builtin_amdgcn_s_setprio(0);                                             \
  }

__device__ __forceinline__ void gemm_core256(
    const unsigned short* __restrict__ A, const unsigned short* __restrict__ B,
    int bm, int bn, int t, unsigned short* LDS /*[4*16384]*/,
    f32x4 acc[8][4]) {
  const int wave = t >> 6, lane = t & 63;
  const int wm = wave >> 2, wn = wave & 3;
  const int quad = lane >> 4, l16 = lane & 15;

  unsigned short* A0 = LDS;
  unsigned short* B0 = LDS + 16384;
  unsigned short* A1 = LDS + 32768;
  unsigned short* B1 = LDS + 49152;

  // staging: linear LDS dest (thread t -> t*16 bytes within chunk), source
  // pre-swizzled: t' = t ^ ((t>>5)&1)<<1  (inverse of st_16x32, involution)
  const int tp = t ^ ((((t >> 5) & 1)) << 1);
  const int srow = tp >> 3, scol = (tp & 7) * 8;
  const unsigned short* Asrc = A + (size_t)(bm * 256 + srow) * NDIM + scol;
  const unsigned short* Bsrc = B + (size_t)(bn * 256 + srow) * NDIM + scol;

  // ds_read: row = {wm*128|wn*64} + frag*16 + l16, so row&4 == l16&4 and the
  // swizzle XOR is lane-constant; fold it into the base byte offset.
  const int swz = (l16 & 4) << 3;
  const int aob = wm * 16384 + l16 * 128 + ((quad * 16) ^ swz);
  const int bob = wn * 8192 + l16 * 128 + ((quad * 16) ^ swz);

  bf16x8 a[4][2], b[4][2];

  // prologue: stage K-tile 0 -> buf0 (8 loads)
#pragma unroll
  for (int c = 0; c < 4; ++c) {
    async_copy16(A0 + c * 4096 + t * 8, Asrc + (size_t)c * 262144);
    async_copy16(B0 + c * 4096 + t * 8, Bsrc + (size_t)c * 262144);
  }

  // K-tiles 0..61 in pairs; 62 and 63 peeled (63 = drain tail).
#pragma unroll 1
  for (int kt = 0; kt < 31; ++kt) {
    const size_t kA = (size_t)(2 * kt + 1) * 64;  // stage T_{2kt+1} -> buf1
    KTILE(A0, B0, A1, B1, kA, 4, true)
    const size_t kB = (size_t)(2 * kt + 2) * 64;  // stage T_{2kt+2} -> buf0
    KTILE(A1, B1, A0, B0, kB, 4, true)
  }
  KTILE(A0, B0, A1, B1, (size_t)4032, 4, true)   // tile 62, stages tile 63
  KTILE(A1, B1, A0, B0, (size_t)0, 0, false)     // tile 63, drain
}

#undef KTILE
#undef MFMA16
#undef RDA
#undef RDB
#undef STG4A
#undef STG4B

// ---- fused q/k/v projection GEMM: grid (16,16,3) --------------------------
// z=0: q=x@Wq.T+bq -> bf16 ; z=1: k -> bf16 ; z=2: v -> fp32
__global__ __launch_bounds__(512, 2) void gemm_qkv(
    const unsigned short* __restrict__ A,
    const unsigned short* __restrict__ B0,
    const unsigned short* __restrict__ B1,
    const unsigned short* __restrict__ B2,
    const float* __restrict__ bias0, const float* __restrict__ bias1,
    const float* __restrict__ bias2,
    unsigned short* __restrict__ qo, unsigned short* __restrict__ ko,
    float* __restrict__ vo) {
  __shared__ __align__(1024) unsigned short LDS[65536];  // 128 KiB

  const int t = threadIdx.x;
  const int bm = blockIdx.y, bn = blockIdx.x, z = blockIdx.z;
  const unsigned short* B = (z == 0) ? B0 : (z == 1) ? B1 : B2;
  const float* bias = (z == 0) ? bias0 : (z == 1) ? bias1 : bias2;

  const f32x4 zero = {0.f, 0.f, 0.f, 0.f};
  f32x4 acc[8][4];
#pragma unroll
  for (int i = 0; i < 8; ++i)
#pragma unroll
    for (int j = 0; j < 4; ++j) acc[i][j] = zero;

  gemm_core256(A, B, bm, bn, t, LDS, acc);

  const int wave = t >> 6, lane = t & 63;
  const int wm = wave >> 2, wn = wave & 3;
  const int quad = lane >> 4, l16 = lane & 15;
  unsigned short* ob = (z == 1) ? ko : qo;  // bf16 dest for z=0/1
#pragma unroll
  for (int j = 0; j < 4; ++j) {
    const int col = bn * 256 + wn * 64 + j * 16 + l16;
    const float bb = bias[col];
#pragma unroll
    for (int i = 0; i < 8; ++i) {
      const int row0 = bm * 256 + wm * 128 + i * 16 + quad * 4;
#pragma unroll
      for (int r = 0; r < 4; ++r) {
        const size_t idx = (size_t)(row0 + r) * NDIM + col;
        const float val = acc[i][j][r] + bb;
        if (z == 2) vo[idx] = val;
        else        ob[idx] = f2bf(val);
      }
    }
  }
}

// ---- S = scale * q@k.T (fp32 out) -----------------------------------------
__global__ __launch_bounds__(512, 2) void gemm_s(
    const unsigned short* __restrict__ A, const unsigned short* __restrict__ B,
    float* __restrict__ C, float scale) {
  __shared__ __align__(1024) unsigned short LDS[65536];  // 128 KiB

  const int t = threadIdx.x;
  const int bm = blockIdx.y, bn = blockIdx.x;

  const f32x4 zero = {0.f, 0.f, 0.f, 0.f};
  f32x4 acc[8][4];
#pragma unroll
  for (int i = 0; i < 8; ++i)
#pragma unroll
    for (int j = 0; j < 4; ++j) acc[i][j] = zero;

  gemm_core256(A, B, bm, bn, t, LDS, acc);

  const int wave = t >> 6, lane = t & 63;
  const int wm = wave >> 2, wn = wave & 3;
  const int quad = lane >> 4, l16 = lane & 15;
#pragma unroll
  for (int j = 0; j < 4; ++j) {
    const int col = bn * 256 + wn * 64 + j * 16 + l16;
#pragma unroll
    for (int i = 0; i < 8; ++i) {
      const int row0 = bm * 256 + wm * 128 + i * 16 + quad * 4;
#pragma unroll
      for (int r = 0; r < 4; ++r)
        C[(size_t)(row0 + r) * NDIM + col] = acc[i][j][r] * scale;
    }
  }
}

// one block per row: out[row][:] = softmax(S[row][:]) * V[row][:]  (in-place ok)
__global__ __launch_bounds__(256) void softmax_mul(
    const float* __restrict__ S, const float* __restrict__ V,
    float* __restrict__ out) {
  const int row = blockIdx.x;
  const int t = threadIdx.x;
  const int lane = t & 63, wave = t >> 6;
  const float4* Sr = (const float4*)(S + (size_t)row * NDIM);
  const float4* Vr = (const float4*)(V + (size_t)row * NDIM);
  float4* Or = (float4*)(out + (size_t)row * NDIM);

  float4 p[4];
  float m = -3.4e38f;
#pragma unroll
  for (int c = 0; c < 4; ++c) {
    p[c] = Sr[t + 256 * c];
    m = fmaxf(m, fmaxf(fmaxf(p[c].x, p[c].y), fmaxf(p[c].z, p[c].w)));
  }
#pragma unroll
  for (int off = 32; off > 0; off >>= 1) m = fmaxf(m, __shfl_xor(m, off));
  __shared__ float redm[4], reds[4];
  if (lane == 0) redm[wave] = m;
  __syncthreads();
  m = fmaxf(fmaxf(redm[0], redm[1]), fmaxf(redm[2], redm[3]));

  float s = 0.f;
#pragma unroll
  for (int c = 0; c < 4; ++c) {
    p[c].x = __expf(p[c].x - m);
    p[c].y = __expf(p[c].y - m);
    p[c].z = __expf(p[c].z - m);
    p[c].w = __expf(p[c].w - m);
    s += (p[c].x + p[c].y) + (p[c].z + p[c].w);
  }
#pragma unroll
  for (int off = 32; off > 0; off >>= 1) s += __shfl_xor(s, off);
  if (lane == 0) reds[wave] = s;
  __syncthreads();
  s = (reds[0] + reds[1]) + (reds[2] + reds[3]);
  const float inv = 1.0f / s;

#pragma unroll
  for (int c = 0; c < 4; ++c) {
    float4 vv = Vr[t + 256 * c];
    float4 o;
    o.x = p[c].x * inv * vv.x;
    o.y = p[c].y * inv * vv.y;
    o.z = p[c].z * inv * vv.z;
    o.w = p[c].w * inv * vv.w;
    Or[t + 256 * c] = o;
  }
}

extern "C" void kernel_launch(void* const* d_in, const int* in_sizes, int n_in,
                              void* d_out, int out_size, void* d_ws, size_t ws_size,
                              hipStream_t stream) {
  const float* x  = (const float*)d_in[0];
  const float* Wq = (const float*)d_in[1];
  const float* bq = (const float*)d_in[2];
  const float* Wk = (const float*)d_in[3];
  const float* bk = (const float*)d_in[4];
  const float* Wv = (const float*)d_in[5];
  const float* bv = (const float*)d_in[6];
  float* out = (float*)d_out;

  const size_t NN = (size_t)NDIM * NDIM;

  unsigned short* xb  = (unsigned short*)d_out;   // x  bf16 (d_out lo)
  unsigned short* wqb = xb + NN;                  // Wq bf16 (d_out hi)
  unsigned short* wkb = (unsigned short*)d_in[1]; // Wk bf16 (Wq-buf lo)
  unsigned short* wvb = wkb + NN;                 // Wv bf16 (Wq-buf hi)
  unsigned short* qb  = (unsigned short*)d_in[3]; // q  bf16 (Wk-buf lo)
  unsigned short* kb  = qb + NN;                  // k  bf16 (Wk-buf hi)
  float*          vf  = (float*)d_in[5];          // v  fp32 (Wv-buf)
  float*          Sf  = (float*)d_out;            // S  fp32 (xb/wqb dead)

  const int cvtBlocks = (int)(NN / (256 * 8));    // 8192

  cvt2_f32_to_bf16<<<dim3(cvtBlocks, 2), 256, 0, stream>>>(x, xb, Wq, wqb);
  cvt2_f32_to_bf16<<<dim3(cvtBlocks, 2), 256, 0, stream>>>(Wk, wkb, Wv, wvb);

  gemm_qkv<<<dim3(16, 16, 3), 512, 0, stream>>>(xb, wqb, wkb, wvb,
                                                bq, bk, bv, qb, kb, vf);

  gemm_s<<<dim3(16, 16), 512, 0, stream>>>(qb, kb, Sf, 0.015625f);

  softmax_mul<<<NDIM, 256, 0, stream>>>(Sf, vf, out);
}

// Round 2
// 736.779 us; speedup vs baseline: 1.2083x; 1.0246x over previous
//
#include <hip/hip_runtime.h>
#include <cstdint>
#include <cstddef>

// Self-attention, DIM=4096, fp32 in/out — zero-workspace, round 6.
//
// Round-6 change vs round 5 (755 us; gemm_qkv 402 us, MfmaUtil 46%,
// SQ_LDS_BANK_CONFLICT 3.8e7): the round-5 swizzle was 1-bit (byte ^=
// (row&4)<<3) — it split the 16 same-column lanes of a ds_read_b128 into
// only 2 groups and left banks 16-31 unused within an instruction (~4 extra
// cycles/read measured). Correct swizzle for a [rows][128B] tile read at
// col = quad*16 with 16 lanes per col (Guideline 4 / m214):
//     physical_byte = logical_byte ^ ((row & 7) << 4)
// -> each col-group's 16 lanes spread over all 8 16B slots, all 32 banks,
// 8 accesses/bank = structural minimum for b128. Read side folds to a
// lane-constant XOR (row&7 == l16&7); k-slice 1 is addr^64. Staging side
// (global_load_lds writes linearly) pre-swizzles the GLOBAL source:
// thread t loads source col ((t ^ (t>>3)) & 7) * 8  (involution).
//
// Schedule (unchanged from round 5): 256² tile, BK=64, 8 waves, 4 phases
// per K-tile {reads 12,4,8,0 b128} + raw s_barrier + counted vmcnt(4)
// once per K-tile (never 0 in-loop) + setprio(1) around 16-MFMA clusters.
// LDS 128 KiB/block, 512 threads, 1 block/CU.
//
// Buffer plan (harness restores d_in before every launch):
//   cvt#1: x -> d_out lo (xb), Wq -> d_out hi (wqb)
//   cvt#2: Wk -> Wq-buf lo (wkb), Wv -> Wq-buf hi (wvb)   [Wq consumed]
//   qkv  : q -> Wk-buf lo (bf16), k -> Wk-buf hi (bf16), v -> Wv-buf (fp32)
//   S    : q@k.T/64 -> d_out (fp32), then softmax*v in place.
//
// Fragment layouts per learn_hip m89/m91:
//   A frag:  A[m = lane&15][k = (lane>>4)*8 + j]   (per 32-wide k-slice)
//   B frag (B^T): B[n = lane&15][k = (lane>>4)*8 + j]
//   C/D: col = lane&15, row = (lane>>4)*4 + reg

#define NDIM 4096

typedef __bf16 bf16x8 __attribute__((ext_vector_type(8)));
typedef float f32x4 __attribute__((ext_vector_type(4)));
typedef unsigned short us8 __attribute__((ext_vector_type(8)));

__device__ __forceinline__ unsigned short f2bf(float f) {
  unsigned int u = __float_as_uint(f);
  return (unsigned short)((u + 0x7fffu + ((u >> 16) & 1u)) >> 16);  // RNE
}

__device__ __forceinline__ void async_copy16(void* lds, const void* g) {
  __builtin_amdgcn_global_load_lds(
      (__attribute__((address_space(1))) void*)(uintptr_t)g,
      (__attribute__((address_space(3))) void*)lds,
      16, 0, 0);
}

// two fp32->bf16 converts in one dispatch (blockIdx.y picks the pair)
__global__ __launch_bounds__(256) void cvt2_f32_to_bf16(
    const float* __restrict__ s0, unsigned short* __restrict__ d0,
    const float* __restrict__ s1, unsigned short* __restrict__ d1) {
  const float* src = blockIdx.y ? s1 : s0;
  unsigned short* dst = blockIdx.y ? d1 : d0;
  const int i = blockIdx.x * 256 + threadIdx.x;  // 8 floats per thread
  const float4* s = (const float4*)src;
  float4 a = s[2 * i];
  float4 b = s[2 * i + 1];
  us8 o;
  o[0] = f2bf(a.x); o[1] = f2bf(a.y); o[2] = f2bf(a.z); o[3] = f2bf(a.w);
  o[4] = f2bf(b.x); o[5] = f2bf(b.y); o[6] = f2bf(b.z); o[7] = f2bf(b.w);
  ((us8*)dst)[i] = o;
}

// ---- 256² / BK=64 / 8-wave / 4-phase counted-vmcnt GEMM core --------------
// LDS layout (ushort units): A0[16384] B0[16384] A1[16384] B1[16384]
// Within each 32 KiB tile: logical [256 rows][64 k] row-major, physical
// byte = logical byte ^ ((row&7)<<4)  (involution, all 32 banks used).

// stage chunks A0,A2,B0,B1 of the NEXT K-tile into the other buffer
#define STG4A(Ao, Bo, kn)                                        \
  async_copy16((Ao) + t * 8,          Asrc + (kn));              \
  async_copy16((Ao) + 8192 + t * 8,   Asrc + (kn) + 524288);     \
  async_copy16((Bo) + t * 8,          Bsrc + (kn));              \
  async_copy16((Bo) + 4096 + t * 8,   Bsrc + (kn) + 262144);

// stage chunks A1,A3,B2,B3
#define STG4B(Ao, Bo, kn)                                        \
  async_copy16((Ao) + 4096 + t * 8,   Asrc + (kn) + 262144);     \
  async_copy16((Ao) + 12288 + t * 8,  Asrc + (kn) + 786432);     \
  async_copy16((Bo) + 8192 + t * 8,   Bsrc + (kn) + 524288);     \
  async_copy16((Bo) + 12288 + t * 8,  Bsrc + (kn) + 786432);

#define RDA(Ac, ROFF)                                                          \
  _Pragma("unroll") for (int i = 0; i < 4; ++i) {                              \
    a[i][0] = *(const bf16x8*)((const char*)(Ac) + (aob + ((ROFF) + i) * 2048));        \
    a[i][1] = *(const bf16x8*)((const char*)(Ac) + ((aob + ((ROFF) + i) * 2048) ^ 64)); \
  }

#define RDB(Bc, J0)                                                            \
  _Pragma("unroll") for (int jj = 0; jj < 2; ++jj) {                           \
    b[(J0) + jj][0] = *(const bf16x8*)((const char*)(Bc) + (bob + ((J0) + jj) * 2048));        \
    b[(J0) + jj][1] = *(const bf16x8*)((const char*)(Bc) + ((bob + ((J0) + jj) * 2048) ^ 64)); \
  }

#define MFMA16(IO, J0)                                                         \
  _Pragma("unroll") for (int i = 0; i < 4; ++i)                                \
  _Pragma("unroll") for (int jj = 0; jj < 2; ++jj)                             \
  _Pragma("unroll") for (int ks = 0; ks < 2; ++ks)                             \
    acc[(IO) + i][(J0) + jj] = __builtin_amdgcn_mfma_f32_16x16x32_bf16(        \
        a[i][ks], b[(J0) + jj][ks], acc[(IO) + i][(J0) + jj], 0, 0, 0);

// One K-tile: compute (Ac,Bc); optionally stage next K-tile into (Ao,Bo).
// VM is a literal token (4 steady-state, 0 for the tail).
#define KTILE(Ac, Bc, Ao, Bo, kn, VM, DOSTAGE)                                 \
  {                                                                            \
    if (DOSTAGE) { STG4A(Ao, Bo, kn) }                                         \
    asm volatile("s_waitcnt vmcnt(" #VM ")" ::: "memory");                     \
    __builtin_amdgcn_s_barrier();                                              \
    __builtin_amdgcn_sched_barrier(0);                                         \
    RDA(Ac, 0)                                                                 \
    RDB(Bc, 0)                                                                 \
    if (DOSTAGE) { STG4B(Ao, Bo, kn) }                                         \
    __builtin_amdgcn_s_barrier();                                              \
    __builtin_amdgcn_sched_barrier(0);                                         \
    __builtin_amdgcn_s_setprio(1);                                             \
    MFMA16(0, 0)                                                               \
    __builtin_amdgcn_s_setprio(0);                                             \
    __builtin_amdgcn_s_barrier();                                              \
    __builtin_amdgcn_sched_barrier(0);                                         \
    RDB(Bc, 2)                                                                 \
    __builtin_amdgcn_s_barrier();                                              \
    __builtin_amdgcn_sched_barrier(0);                                         \
    __builtin_amdgcn_s_setprio(1);                                             \
    MFMA16(0, 2)                                                               \
    __builtin_amdgcn_s_setprio(0);                                             \
    __builtin_amdgcn_s_barrier();                                              \
    __builtin_amdgcn_sched_barrier(0);                                         \
    RDA(Ac, 4)                                                                 \
    __builtin_amdgcn_s_barrier();                                              \
    __builtin_amdgcn_sched_barrier(0);                                         \
    __builtin_amdgcn_s_setprio(1);                                             \
    MFMA16(4, 2)                                                               \
    __builtin_amdgcn_s_setprio(0);                                             \
    __builtin_amdgcn_s_barrier();                                              \
    __builtin_amdgcn_sched_barrier(0);                                         \
    __builtin_amdgcn_s_setprio(1);                                             \
    MFMA16(4, 0)                                                               \
    __builtin_amdgcn_s_setprio(0);                                             \
  }

__device__ __forceinline__ void gemm_core256(
    const unsigned short* __restrict__ A, const unsigned short* __restrict__ B,
    int bm, int bn, int t, unsigned short* LDS /*[4*16384]*/,
    f32x4 acc[8][4]) {
  const int wave = t >> 6, lane = t & 63;
  const int wm = wave >> 2, wn = wave & 3;
  const int quad = lane >> 4, l16 = lane & 15;

  unsigned short* A0 = LDS;
  unsigned short* B0 = LDS + 16384;
  unsigned short* A1 = LDS + 32768;
  unsigned short* B1 = LDS + 49152;

  // staging: linear LDS dest (thread t -> bytes [t*16, t*16+16) within its
  // 64-row chunk => physical row t>>3, 16B-unit t&7). Physical unit u of row
  // r must hold logical unit u ^ (r&7), so the GLOBAL source col is
  // ((t ^ (t>>3)) & 7) * 8 elements (involution of the read-side XOR).
  const int srow = t >> 3;
  const int scol = ((t ^ (t >> 3)) & 7) * 8;
  const unsigned short* Asrc = A + (size_t)(bm * 256 + srow) * NDIM + scol;
  const unsigned short* Bsrc = B + (size_t)(bn * 256 + srow) * NDIM + scol;

  // ds_read: row = {wm*128|wn*64} + frag*16 + l16 -> row&7 == l16&7, so the
  // swizzle XOR ((row&7)<<4) is lane-constant; fold into the base byte
  // offset. k-slice 1 (+64B) commutes with the XOR as addr^64.
  const int colx = (quad * 16) ^ ((l16 & 7) << 4);
  const int aob = wm * 16384 + l16 * 128 + colx;
  const int bob = wn * 8192 + l16 * 128 + colx;

  bf16x8 a[4][2], b[4][2];

  // prologue: stage K-tile 0 -> buf0 (8 loads)
#pragma unroll
  for (int c = 0; c < 4; ++c) {
    async_copy16(A0 + c * 4096 + t * 8, Asrc + (size_t)c * 262144);
    async_copy16(B0 + c * 4096 + t * 8, Bsrc + (size_t)c * 262144);
  }

  // K-tiles 0..61 in pairs; 62 and 63 peeled (63 = drain tail).
#pragma unroll 1
  for (int kt = 0; kt < 31; ++kt) {
    const size_t kA = (size_t)(2 * kt + 1) * 64;  // stage T_{2kt+1} -> buf1
    KTILE(A0, B0, A1, B1, kA, 4, true)
    const size_t kB = (size_t)(2 * kt + 2) * 64;  // stage T_{2kt+2} -> buf0
    KTILE(A1, B1, A0, B0, kB, 4, true)
  }
  KTILE(A0, B0, A1, B1, (size_t)4032, 4, true)   // tile 62, stages tile 63
  KTILE(A1, B1, A0, B0, (size_t)0, 0, false)     // tile 63, drain
}

#undef KTILE
#undef MFMA16
#undef RDA
#undef RDB
#undef STG4A
#undef STG4B

// ---- fused q/k/v projection GEMM: grid (16,16,3) --------------------------
// z=0: q=x@Wq.T+bq -> bf16 ; z=1: k -> bf16 ; z=2: v -> fp32
__global__ __launch_bounds__(512, 2) void gemm_qkv(
    const unsigned short* __restrict__ A,
    const unsigned short* __restrict__ B0,
    const unsigned short* __restrict__ B1,
    const unsigned short* __restrict__ B2,
    const float* __restrict__ bias0, const float* __restrict__ bias1,
    const float* __restrict__ bias2,
    unsigned short* __restrict__ qo, unsigned short* __restrict__ ko,
    float* __restrict__ vo) {
  __shared__ __align__(1024) unsigned short LDS[65536];  // 128 KiB

  const int t = threadIdx.x;
  const int bm = blockIdx.y, bn = blockIdx.x, z = blockIdx.z;
  const unsigned short* B = (z == 0) ? B0 : (z == 1) ? B1 : B2;
  const float* bias = (z == 0) ? bias0 : (z == 1) ? bias1 : bias2;

  const f32x4 zero = {0.f, 0.f, 0.f, 0.f};
  f32x4 acc[8][4];
#pragma unroll
  for (int i = 0; i < 8; ++i)
#pragma unroll
    for (int j = 0; j < 4; ++j) acc[i][j] = zero;

  gemm_core256(A, B, bm, bn, t, LDS, acc);

  const int wave = t >> 6, lane = t & 63;
  const int wm = wave >> 2, wn = wave & 3;
  const int quad = lane >> 4, l16 = lane & 15;
  unsigned short* ob = (z == 1) ? ko : qo;  // bf16 dest for z=0/1
#pragma unroll
  for (int j = 0; j < 4; ++j) {
    const int col = bn * 256 + wn * 64 + j * 16 + l16;
    const float bb = bias[col];
#pragma unroll
    for (int i = 0; i < 8; ++i) {
      const int row0 = bm * 256 + wm * 128 + i * 16 + quad * 4;
#pragma unroll
      for (int r = 0; r < 4; ++r) {
        const size_t idx = (size_t)(row0 + r) * NDIM + col;
        const float val = acc[i][j][r] + bb;
        if (z == 2) vo[idx] = val;
        else        ob[idx] = f2bf(val);
      }
    }
  }
}

// ---- S = scale * q@k.T (fp32 out) -----------------------------------------
__global__ __launch_bounds__(512, 2) void gemm_s(
    const unsigned short* __restrict__ A, const unsigned short* __restrict__ B,
    float* __restrict__ C, float scale) {
  __shared__ __align__(1024) unsigned short LDS[65536];  // 128 KiB

  const int t = threadIdx.x;
  const int bm = blockIdx.y, bn = blockIdx.x;

  const f32x4 zero = {0.f, 0.f, 0.f, 0.f};
  f32x4 acc[8][4];
#pragma unroll
  for (int i = 0; i < 8; ++i)
#pragma unroll
    for (int j = 0; j < 4; ++j) acc[i][j] = zero;

  gemm_core256(A, B, bm, bn, t, LDS, acc);

  const int wave = t >> 6, lane = t & 63;
  const int wm = wave >> 2, wn = wave & 3;
  const int quad = lane >> 4, l16 = lane & 15;
#pragma unroll
  for (int j = 0; j < 4; ++j) {
    const int col = bn * 256 + wn * 64 + j * 16 + l16;
#pragma unroll
    for (int i = 0; i < 8; ++i) {
      const int row0 = bm * 256 + wm * 128 + i * 16 + quad * 4;
#pragma unroll
      for (int r = 0; r < 4; ++r)
        C[(size_t)(row0 + r) * NDIM + col] = acc[i][j][r] * scale;
    }
  }
}

// one block per row: out[row][:] = softmax(S[row][:]) * V[row][:]  (in-place ok)
__global__ __launch_bounds__(256) void softmax_mul(
    const float* __restrict__ S, const float* __restrict__ V,
    float* __restrict__ out) {
  const int row = blockIdx.x;
  const int t = threadIdx.x;
  const int lane = t & 63, wave = t >> 6;
  const float4* Sr = (const float4*)(S + (size_t)row * NDIM);
  const float4* Vr = (const float4*)(V + (size_t)row * NDIM);
  float4* Or = (float4*)(out + (size_t)row * NDIM);

  float4 p[4];
  float m = -3.4e38f;
#pragma unroll
  for (int c = 0; c < 4; ++c) {
    p[c] = Sr[t + 256 * c];
    m = fmaxf(m, fmaxf(fmaxf(p[c].x, p[c].y), fmaxf(p[c].z, p[c].w)));
  }
#pragma unroll
  for (int off = 32; off > 0; off >>= 1) m = fmaxf(m, __shfl_xor(m, off));
  __shared__ float redm[4], reds[4];
  if (lane == 0) redm[wave] = m;
  __syncthreads();
  m = fmaxf(fmaxf(redm[0], redm[1]), fmaxf(redm[2], redm[3]));

  float s = 0.f;
#pragma unroll
  for (int c = 0; c < 4; ++c) {
    p[c].x = __expf(p[c].x - m);
    p[c].y = __expf(p[c].y - m);
    p[c].z = __expf(p[c].z - m);
    p[c].w = __expf(p[c].w - m);
    s += (p[c].x + p[c].y) + (p[c].z + p[c].w);
  }
#pragma unroll
  for (int off = 32; off > 0; off >>= 1) s += __shfl_xor(s, off);
  if (lane == 0) reds[wave] = s;
  __syncthreads();
  s = (reds[0] + reds[1]) + (reds[2] + reds[3]);
  const float inv = 1.0f / s;

#pragma unroll
  for (int c = 0; c < 4; ++c) {
    float4 vv = Vr[t + 256 * c];
    float4 o;
    o.x = p[c].x * inv * vv.x;
    o.y = p[c].y * inv * vv.y;
    o.z = p[c].z * inv * vv.z;
    o.w = p[c].w * inv * vv.w;
    Or[t + 256 * c] = o;
  }
}

extern "C" void kernel_launch(void* const* d_in, const int* in_sizes, int n_in,
                              void* d_out, int out_size, void* d_ws, size_t ws_size,
                              hipStream_t stream) {
  const float* x  = (const float*)d_in[0];
  const float* Wq = (const float*)d_in[1];
  const float* bq = (const float*)d_in[2];
  const float* Wk = (const float*)d_in[3];
  const float* bk = (const float*)d_in[4];
  const float* Wv = (const float*)d_in[5];
  const float* bv = (const float*)d_in[6];
  float* out = (float*)d_out;

  const size_t NN = (size_t)NDIM * NDIM;

  unsigned short* xb  = (unsigned short*)d_out;   // x  bf16 (d_out lo)
  unsigned short* wqb = xb + NN;                  // Wq bf16 (d_out hi)
  unsigned short* wkb = (unsigned short*)d_in[1]; // Wk bf16 (Wq-buf lo)
  unsigned short* wvb = wkb + NN;                 // Wv bf16 (Wq-buf hi)
  unsigned short* qb  = (unsigned short*)d_in[3]; // q  bf16 (Wk-buf lo)
  unsigned short* kb  = qb + NN;                  // k  bf16 (Wk-buf hi)
  float*          vf  = (float*)d_in[5];          // v  fp32 (Wv-buf)
  float*          Sf  = (float*)d_out;            // S  fp32 (xb/wqb dead)

  const int cvtBlocks = (int)(NN / (256 * 8));    // 8192

  cvt2_f32_to_bf16<<<dim3(cvtBlocks, 2), 256, 0, stream>>>(x, xb, Wq, wqb);
  cvt2_f32_to_bf16<<<dim3(cvtBlocks, 2), 256, 0, stream>>>(Wk, wkb, Wv, wvb);

  gemm_qkv<<<dim3(16, 16, 3), 512, 0, stream>>>(xb, wqb, wkb, wvb,
                                                bq, bk, bv, qb, kb, vf);

  gemm_s<<<dim3(16, 16), 512, 0, stream>>>(qb, kb, Sf, 0.015625f);

  softmax_mul<<<NDIM, 256, 0, stream>>>(Sf, vf, out);
}

// Round 3
// 717.988 us; speedup vs baseline: 1.2399x; 1.0262x over previous
//
#include <hip/hip_runtime.h>
#include <cstdint>
#include <cstddef>

// Self-attention, DIM=4096, fp32 in/out — zero-workspace, round 7.
//
// Round-7 change vs round 6 (737 us; gemm_qkv 379 us, MfmaUtil 49.5%,
// SQ_LDS_BANK_CONFLICT 0): round-6 cycle accounting showed per K-tile
// wall 4730 cyc = MFMA 2483 + LDS-read 2390 STRICTLY ADDITIVE — the 8
// s_barrier + sched_barrier(0) fences per K-tile partitioned reads and
// MFMAs into rigid alternating windows (DS pipe idle during MFMA windows
// and vice versa; m141's order-pinning lesson). New K-tile has the
// provably-minimal sync: ONE vmcnt(0) + ONE s_barrier + ONE
// sched_barrier(0); the body (8 stage-issues, 24 ds_read_b128, 64 MFMA)
// is a single scheduling region — the compiler interleaves with counted
// lgkmcnt so the DS pipe drains UNDER the MFMA pipe.
//   Sync proof: vmcnt(0) precedes the barrier -> when any wave passes,
//   every wave's stage loads for this tile have landed. Stage loads for
//   tile t+1 are issued AFTER the barrier; at the barrier every wave has
//   lgkm-consumed all its prior-tile reads of the target buffer (each
//   frag feeds an MFMA inside that window) -> no write/read race.
//   vmcnt(0) is exact, not a drain: the only outstanding loads at the
//   wait are the 8 this tile needs (issued a full tile earlier).
//
// Kept from round 6: 256² tile, BK=64, 8 waves (2Mx4N), swizzle
// physical_byte = logical ^ ((row&7)<<4) (conflict-free, read side folds
// to lane-const XOR, staging pre-swizzles the global source), setprio(1)
// around MFMA clusters, LDS 128 KiB, 512 threads, 1 block/CU.
//
// Buffer plan (harness restores d_in before every launch):
//   cvt#1: x -> d_out lo (xb), Wq -> d_out hi (wqb)
//   cvt#2: Wk -> Wq-buf lo (wkb), Wv -> Wq-buf hi (wvb)   [Wq consumed]
//   qkv  : q -> Wk-buf lo (bf16), k -> Wk-buf hi (bf16), v -> Wv-buf (fp32)
//   S    : q@k.T/64 -> d_out (fp32), then softmax*v in place.
//
// Fragment layouts per learn_hip m89/m91:
//   A frag:  A[m = lane&15][k = (lane>>4)*8 + j]   (per 32-wide k-slice)
//   B frag (B^T): B[n = lane&15][k = (lane>>4)*8 + j]
//   C/D: col = lane&15, row = (lane>>4)*4 + reg

#define NDIM 4096

typedef __bf16 bf16x8 __attribute__((ext_vector_type(8)));
typedef float f32x4 __attribute__((ext_vector_type(4)));
typedef unsigned short us8 __attribute__((ext_vector_type(8)));

__device__ __forceinline__ unsigned short f2bf(float f) {
  unsigned int u = __float_as_uint(f);
  return (unsigned short)((u + 0x7fffu + ((u >> 16) & 1u)) >> 16);  // RNE
}

__device__ __forceinline__ void async_copy16(void* lds, const void* g) {
  __builtin_amdgcn_global_load_lds(
      (__attribute__((address_space(1))) void*)(uintptr_t)g,
      (__attribute__((address_space(3))) void*)lds,
      16, 0, 0);
}

// two fp32->bf16 converts in one dispatch (blockIdx.y picks the pair)
__global__ __launch_bounds__(256) void cvt2_f32_to_bf16(
    const float* __restrict__ s0, unsigned short* __restrict__ d0,
    const float* __restrict__ s1, unsigned short* __restrict__ d1) {
  const float* src = blockIdx.y ? s1 : s0;
  unsigned short* dst = blockIdx.y ? d1 : d0;
  const int i = blockIdx.x * 256 + threadIdx.x;  // 8 floats per thread
  const float4* s = (const float4*)src;
  float4 a = s[2 * i];
  float4 b = s[2 * i + 1];
  us8 o;
  o[0] = f2bf(a.x); o[1] = f2bf(a.y); o[2] = f2bf(a.z); o[3] = f2bf(a.w);
  o[4] = f2bf(b.x); o[5] = f2bf(b.y); o[6] = f2bf(b.z); o[7] = f2bf(b.w);
  ((us8*)dst)[i] = o;
}

// ---- 256² / BK=64 / 8-wave / loose-body counted-vmcnt GEMM core -----------
// LDS layout (ushort units): A0[16384] B0[16384] A1[16384] B1[16384]
// Within each 32 KiB tile: logical [256 rows][64 k] row-major, physical
// byte = logical byte ^ ((row&7)<<4)  (involution, all 32 banks used).

// stage the full NEXT K-tile (8 x global_load_lds dwordx4 per thread-group)
#define STG8(Ao, Bo, kn)                                         \
  async_copy16((Ao) + t * 8,          Asrc + (kn));              \
  async_copy16((Ao) + 4096 + t * 8,   Asrc + (kn) + 262144);     \
  async_copy16((Ao) + 8192 + t * 8,   Asrc + (kn) + 524288);     \
  async_copy16((Ao) + 12288 + t * 8,  Asrc + (kn) + 786432);     \
  async_copy16((Bo) + t * 8,          Bsrc + (kn));              \
  async_copy16((Bo) + 4096 + t * 8,   Bsrc + (kn) + 262144);     \
  async_copy16((Bo) + 8192 + t * 8,   Bsrc + (kn) + 524288);     \
  async_copy16((Bo) + 12288 + t * 8,  Bsrc + (kn) + 786432);

#define RDA(Ac, ROFF)                                                          \
  _Pragma("unroll") for (int i = 0; i < 4; ++i) {                              \
    a[i][0] = *(const bf16x8*)((const char*)(Ac) + (aob + ((ROFF) + i) * 2048));        \
    a[i][1] = *(const bf16x8*)((const char*)(Ac) + ((aob + ((ROFF) + i) * 2048) ^ 64)); \
  }

#define RDB(Bc, J0)                                                            \
  _Pragma("unroll") for (int jj = 0; jj < 2; ++jj) {                           \
    b[(J0) + jj][0] = *(const bf16x8*)((const char*)(Bc) + (bob + ((J0) + jj) * 2048));        \
    b[(J0) + jj][1] = *(const bf16x8*)((const char*)(Bc) + ((bob + ((J0) + jj) * 2048) ^ 64)); \
  }

#define MFMA16(IO, J0)                                                         \
  _Pragma("unroll") for (int i = 0; i < 4; ++i)                                \
  _Pragma("unroll") for (int jj = 0; jj < 2; ++jj)                             \
  _Pragma("unroll") for (int ks = 0; ks < 2; ++ks)                             \
    acc[(IO) + i][(J0) + jj] = __builtin_amdgcn_mfma_f32_16x16x32_bf16(        \
        a[i][ks], b[(J0) + jj][ks], acc[(IO) + i][(J0) + jj], 0, 0, 0);

// One K-tile: compute (Ac,Bc); optionally stage next K-tile into (Ao,Bo).
// Single sync point; body is one free scheduling region.
#define KTILE(Ac, Bc, Ao, Bo, kn, DOSTAGE)                                     \
  {                                                                            \
    asm volatile("s_waitcnt vmcnt(0)" ::: "memory");                           \
    __builtin_amdgcn_s_barrier();                                              \
    __builtin_amdgcn_sched_barrier(0);                                         \
    if (DOSTAGE) { STG8(Ao, Bo, kn) }                                          \
    RDA(Ac, 0)                                                                 \
    RDB(Bc, 0)                                                                 \
    __builtin_amdgcn_s_setprio(1);                                             \
    MFMA16(0, 0)                                                               \
    __builtin_amdgcn_s_setprio(0);                                             \
    RDB(Bc, 2)                                                                 \
    __builtin_amdgcn_s_setprio(1);                                             \
    MFMA16(0, 2)                                                               \
    __builtin_amdgcn_s_setprio(0);                                             \
    RDA(Ac, 4)                                                                 \
    __builtin_amdgcn_s_setprio(1);                                             \
    MFMA16(4, 2)                                                               \
    MFMA16(4, 0)                                                               \
    __builtin_amdgcn_s_setprio(0);                                             \
  }

__device__ __forceinline__ void gemm_core256(
    const unsigned short* __restrict__ A, const unsigned short* __restrict__ B,
    int bm, int bn, int t, unsigned short* LDS /*[4*16384]*/,
    f32x4 acc[8][4]) {
  const int wave = t >> 6, lane = t & 63;
  const int wm = wave >> 2, wn = wave & 3;
  const int quad = lane >> 4, l16 = lane & 15;

  unsigned short* A0 = LDS;
  unsigned short* B0 = LDS + 16384;
  unsigned short* A1 = LDS + 32768;
  unsigned short* B1 = LDS + 49152;

  // staging: linear LDS dest (thread t -> bytes [t*16, t*16+16) within its
  // 64-row chunk => physical row t>>3, 16B-unit t&7). Physical unit u of row
  // r must hold logical unit u ^ (r&7), so the GLOBAL source col is
  // ((t ^ (t>>3)) & 7) * 8 elements (involution of the read-side XOR).
  const int srow = t >> 3;
  const int scol = ((t ^ (t >> 3)) & 7) * 8;
  const unsigned short* Asrc = A + (size_t)(bm * 256 + srow) * NDIM + scol;
  const unsigned short* Bsrc = B + (size_t)(bn * 256 + srow) * NDIM + scol;

  // ds_read: row = {wm*128|wn*64} + frag*16 + l16 -> row&7 == l16&7, so the
  // swizzle XOR ((row&7)<<4) is lane-constant; fold into the base byte
  // offset. k-slice 1 (+64B) commutes with the XOR as addr^64.
  const int colx = (quad * 16) ^ ((l16 & 7) << 4);
  const int aob = wm * 16384 + l16 * 128 + colx;
  const int bob = wn * 8192 + l16 * 128 + colx;

  bf16x8 a[4][2], b[4][2];

  // prologue: stage K-tile 0 -> buf0 (8 loads)
#pragma unroll
  for (int c = 0; c < 4; ++c) {
    async_copy16(A0 + c * 4096 + t * 8, Asrc + (size_t)c * 262144);
    async_copy16(B0 + c * 4096 + t * 8, Bsrc + (size_t)c * 262144);
  }

  // K-tiles 0..61 in pairs; 62 and 63 peeled (63 = drain tail).
#pragma unroll 1
  for (int kt = 0; kt < 31; ++kt) {
    const size_t kA = (size_t)(2 * kt + 1) * 64;  // stage T_{2kt+1} -> buf1
    KTILE(A0, B0, A1, B1, kA, true)
    const size_t kB = (size_t)(2 * kt + 2) * 64;  // stage T_{2kt+2} -> buf0
    KTILE(A1, B1, A0, B0, kB, true)
  }
  KTILE(A0, B0, A1, B1, (size_t)4032, true)   // tile 62, stages tile 63
  KTILE(A1, B1, A0, B0, (size_t)0, false)     // tile 63, drain
}

#undef KTILE
#undef MFMA16
#undef RDA
#undef RDB
#undef STG8

// ---- fused q/k/v projection GEMM: grid (16,16,3) --------------------------
// z=0: q=x@Wq.T+bq -> bf16 ; z=1: k -> bf16 ; z=2: v -> fp32
__global__ __launch_bounds__(512, 2) void gemm_qkv(
    const unsigned short* __restrict__ A,
    const unsigned short* __restrict__ B0,
    const unsigned short* __restrict__ B1,
    const unsigned short* __restrict__ B2,
    const float* __restrict__ bias0, const float* __restrict__ bias1,
    const float* __restrict__ bias2,
    unsigned short* __restrict__ qo, unsigned short* __restrict__ ko,
    float* __restrict__ vo) {
  __shared__ __align__(1024) unsigned short LDS[65536];  // 128 KiB

  const int t = threadIdx.x;
  const int bm = blockIdx.y, bn = blockIdx.x, z = blockIdx.z;
  const unsigned short* B = (z == 0) ? B0 : (z == 1) ? B1 : B2;
  const float* bias = (z == 0) ? bias0 : (z == 1) ? bias1 : bias2;

  const f32x4 zero = {0.f, 0.f, 0.f, 0.f};
  f32x4 acc[8][4];
#pragma unroll
  for (int i = 0; i < 8; ++i)
#pragma unroll
    for (int j = 0; j < 4; ++j) acc[i][j] = zero;

  gemm_core256(A, B, bm, bn, t, LDS, acc);

  const int wave = t >> 6, lane = t & 63;
  const int wm = wave >> 2, wn = wave & 3;
  const int quad = lane >> 4, l16 = lane & 15;
  unsigned short* ob = (z == 1) ? ko : qo;  // bf16 dest for z=0/1
#pragma unroll
  for (int j = 0; j < 4; ++j) {
    const int col = bn * 256 + wn * 64 + j * 16 + l16;
    const float bb = bias[col];
#pragma unroll
    for (int i = 0; i < 8; ++i) {
      const int row0 = bm * 256 + wm * 128 + i * 16 + quad * 4;
#pragma unroll
      for (int r = 0; r < 4; ++r) {
        const size_t idx = (size_t)(row0 + r) * NDIM + col;
        const float val = acc[i][j][r] + bb;
        if (z == 2) vo[idx] = val;
        else        ob[idx] = f2bf(val);
      }
    }
  }
}

// ---- S = scale * q@k.T (fp32 out) -----------------------------------------
__global__ __launch_bounds__(512, 2) void gemm_s(
    const unsigned short* __restrict__ A, const unsigned short* __restrict__ B,
    float* __restrict__ C, float scale) {
  __shared__ __align__(1024) unsigned short LDS[65536];  // 128 KiB

  const int t = threadIdx.x;
  const int bm = blockIdx.y, bn = blockIdx.x;

  const f32x4 zero = {0.f, 0.f, 0.f, 0.f};
  f32x4 acc[8][4];
#pragma unroll
  for (int i = 0; i < 8; ++i)
#pragma unroll
    for (int j = 0; j < 4; ++j) acc[i][j] = zero;

  gemm_core256(A, B, bm, bn, t, LDS, acc);

  const int wave = t >> 6, lane = t & 63;
  const int wm = wave >> 2, wn = wave & 3;
  const int quad = lane >> 4, l16 = lane & 15;
#pragma unroll
  for (int j = 0; j < 4; ++j) {
    const int col = bn * 256 + wn * 64 + j * 16 + l16;
#pragma unroll
    for (int i = 0; i < 8; ++i) {
      const int row0 = bm * 256 + wm * 128 + i * 16 + quad * 4;
#pragma unroll
      for (int r = 0; r < 4; ++r)
        C[(size_t)(row0 + r) * NDIM + col] = acc[i][j][r] * scale;
    }
  }
}

// one block per row: out[row][:] = softmax(S[row][:]) * V[row][:]  (in-place ok)
__global__ __launch_bounds__(256) void softmax_mul(
    const float* __restrict__ S, const float* __restrict__ V,
    float* __restrict__ out) {
  const int row = blockIdx.x;
  const int t = threadIdx.x;
  const int lane = t & 63, wave = t >> 6;
  const float4* Sr = (const float4*)(S + (size_t)row * NDIM);
  const float4* Vr = (const float4*)(V + (size_t)row * NDIM);
  float4* Or = (float4*)(out + (size_t)row * NDIM);

  float4 p[4];
  float m = -3.4e38f;
#pragma unroll
  for (int c = 0; c < 4; ++c) {
    p[c] = Sr[t + 256 * c];
    m = fmaxf(m, fmaxf(fmaxf(p[c].x, p[c].y), fmaxf(p[c].z, p[c].w)));
  }
#pragma unroll
  for (int off = 32; off > 0; off >>= 1) m = fmaxf(m, __shfl_xor(m, off));
  __shared__ float redm[4], reds[4];
  if (lane == 0) redm[wave] = m;
  __syncthreads();
  m = fmaxf(fmaxf(redm[0], redm[1]), fmaxf(redm[2], redm[3]));

  float s = 0.f;
#pragma unroll
  for (int c = 0; c < 4; ++c) {
    p[c].x = __expf(p[c].x - m);
    p[c].y = __expf(p[c].y - m);
    p[c].z = __expf(p[c].z - m);
    p[c].w = __expf(p[c].w - m);
    s += (p[c].x + p[c].y) + (p[c].z + p[c].w);
  }
#pragma unroll
  for (int off = 32; off > 0; off >>= 1) s += __shfl_xor(s, off);
  if (lane == 0) reds[wave] = s;
  __syncthreads();
  s = (reds[0] + reds[1]) + (reds[2] + reds[3]);
  const float inv = 1.0f / s;

#pragma unroll
  for (int c = 0; c < 4; ++c) {
    float4 vv = Vr[t + 256 * c];
    float4 o;
    o.x = p[c].x * inv * vv.x;
    o.y = p[c].y * inv * vv.y;
    o.z = p[c].z * inv * vv.z;
    o.w = p[c].w * inv * vv.w;
    Or[t + 256 * c] = o;
  }
}

extern "C" void kernel_launch(void* const* d_in, const int* in_sizes, int n_in,
                              void* d_out, int out_size, void* d_ws, size_t ws_size,
                              hipStream_t stream) {
  const float* x  = (const float*)d_in[0];
  const float* Wq = (const float*)d_in[1];
  const float* bq = (const float*)d_in[2];
  const float* Wk = (const float*)d_in[3];
  const float* bk = (const float*)d_in[4];
  const float* Wv = (const float*)d_in[5];
  const float* bv = (const float*)d_in[6];
  float* out = (float*)d_out;

  const size_t NN = (size_t)NDIM * NDIM;

  unsigned short* xb  = (unsigned short*)d_out;   // x  bf16 (d_out lo)
  unsigned short* wqb = xb + NN;                  // Wq bf16 (d_out hi)
  unsigned short* wkb = (unsigned short*)d_in[1]; // Wk bf16 (Wq-buf lo)
  unsigned short* wvb = wkb + NN;                 // Wv bf16 (Wq-buf hi)
  unsigned short* qb  = (unsigned short*)d_in[3]; // q  bf16 (Wk-buf lo)
  unsigned short* kb  = qb + NN;                  // k  bf16 (Wk-buf hi)
  float*          vf  = (float*)d_in[5];          // v  fp32 (Wv-buf)
  float*          Sf  = (float*)d_out;            // S  fp32 (xb/wqb dead)

  const int cvtBlocks = (int)(NN / (256 * 8));    // 8192

  cvt2_f32_to_bf16<<<dim3(cvtBlocks, 2), 256, 0, stream>>>(x, xb, Wq, wqb);
  cvt2_f32_to_bf16<<<dim3(cvtBlocks, 2), 256, 0, stream>>>(Wk, wkb, Wv, wvb);

  gemm_qkv<<<dim3(16, 16, 3), 512, 0, stream>>>(xb, wqb, wkb, wvb,
                                                bq, bk, bv, qb, kb, vf);

  gemm_s<<<dim3(16, 16), 512, 0, stream>>>(qb, kb, Sf, 0.015625f);

  softmax_mul<<<NDIM, 256, 0, stream>>>(Sf, vf, out);
}